// Round 6
// baseline (1382.980 us; speedup 1.0000x reference)
//
#include <hip/hip_runtime.h>
#include <hip/hip_bf16.h>
#include <stdint.h>

// CrossExpertRefinement on MI355X — round 6: expert-major S layout.
// bf16x3 split-GEMM, plane-tiled hi/lo operands, global_load_lds double-buffer
// pipeline with counted vmcnt(8), source-side swizzle, bijective XCD bands,
// fused LN / bias / residual epilogues. S row = e*16384 + t (expert-major):
// K1 writes and K5 reads contiguous; chunk path uses a 2-level row mapping.
//
// Plane-tiled operand layout: element (row,k) hi byte =
//   base + (2*(k>>5))*R*64 + row*64 + (k&31)*2 ; lo plane at +R*64.

using bf16   = __bf16;
using bf16x8 = __attribute__((ext_vector_type(8))) __bf16;
using f32x16 = __attribute__((ext_vector_type(16))) float;

#define GLOAD16(g, l) __builtin_amdgcn_global_load_lds(                        \
    (const __attribute__((address_space(1))) unsigned int*)(g),                \
    (__attribute__((address_space(3))) unsigned int*)(l), 16, 0, 0)

// two-level logical-row -> physical-row map: sub-blocks of 2^subShift rows
// are contiguous (stride 1), blocks are bigStride apart.
struct Op { const char* base; int R; int row0; int subShift; int bigStride; };

__device__ __forceinline__ size_t rowOf(const Op& o, int m) {
    return (size_t)o.row0 + (size_t)(m >> o.subShift) * (size_t)o.bigStride
         + (size_t)(m & ((1u << o.subShift) - 1));
}

// ---------------------------------------------------------------------------
// fp32 (R x K, ld=ldin) -> plane-tiled hi/lo bf16, zero-padded to Rp x Kp.
__global__ __launch_bounds__(256) void split_tiled(
    const float* __restrict__ in, int R, int K, int ldin,
    char* __restrict__ outb, int Rp, int Kp, const float* __restrict__ cs)
{
    const size_t ps = (size_t)Rp * 64;
    const int total8 = (Rp * Kp) >> 3;
    for (int idx = blockIdx.x * 256 + threadIdx.x; idx < total8;
         idx += gridDim.x * 256) {
        const int r  = (idx << 3) / Kp;
        const int k8 = (idx << 3) - r * Kp;
        float v[8];
#pragma unroll
        for (int j = 0; j < 8; ++j) {
            const int k = k8 + j;
            float x = (r < R && k < K) ? in[(size_t)r * ldin + k] : 0.f;
            if (cs && k < K) x *= cs[k];
            v[j] = x;
        }
        bf16x8 h8, l8;
#pragma unroll
        for (int j = 0; j < 8; ++j) {
            const bf16 h = (bf16)v[j];
            h8[j] = h;
            l8[j] = (bf16)(v[j] - (float)h);
        }
        char* hp = outb + (size_t)(2 * (k8 >> 5)) * ps + (size_t)r * 64 + (k8 & 31) * 2;
        *(bf16x8*)hp = h8;
        *(bf16x8*)(hp + ps) = l8;
    }
}

// u[n] = Wqkv[n,:]·ln_g ; c[n] = Wqkv[n,:]·ln_b + bqkv[n]
__global__ __launch_bounds__(256) void qkv_uc(
    const float* __restrict__ W, const float* __restrict__ g,
    const float* __restrict__ b, const float* __restrict__ bq,
    float* __restrict__ u, float* __restrict__ c)
{
    const int n = blockIdx.x * 4 + (threadIdx.x >> 6);
    const int lane = threadIdx.x & 63;
    float su = 0.f, sc = 0.f;
#pragma unroll
    for (int j = 0; j < 8; ++j) {
        const int k = lane * 8 + j;
        const float w = W[(size_t)n * 512 + k];
        su += w * g[k];
        sc += w * b[k];
    }
#pragma unroll
    for (int o = 32; o > 0; o >>= 1) { su += __shfl_xor(su, o); sc += __shfl_xor(sc, o); }
    if (lane == 0) { u[n] = su; c[n] = sc + bq[n]; }
}

// Per-row LN stats from plane-tiled S (Kp=512). One wave per row.
__global__ __launch_bounds__(256) void ln_stats_t(
    const char* __restrict__ St, int R, float* __restrict__ mu, float* __restrict__ rstd)
{
    const int row = blockIdx.x * 4 + (threadIdx.x >> 6);
    const int lane = threadIdx.x & 63;
    const int kt = lane >> 2, qq = lane & 3;
    const size_t ps = (size_t)R * 64;
    const char* hp = St + (size_t)(2 * kt) * ps + (size_t)row * 64 + qq * 16;
    const bf16x8 h = *(const bf16x8*)hp;
    const bf16x8 l = *(const bf16x8*)(hp + ps);
    float s = 0.f, q = 0.f;
#pragma unroll
    for (int j = 0; j < 8; ++j) {
        const float v = (float)h[j] + (float)l[j];
        s += v; q += v * v;
    }
#pragma unroll
    for (int o = 32; o > 0; o >>= 1) { s += __shfl_xor(s, o); q += __shfl_xor(q, o); }
    if (lane == 0) {
        const float m = s * (1.f / 512.f);
        mu[row] = m;
        rstd[row] = rsqrtf(q * (1.f / 512.f) - m * m + 1e-5f);
    }
}

// ---------------------------------------------------------------------------
// GEMM C[m,n] = sum_k A[m,k]*B[n,k]; A,B plane-tiled hi/lo bf16 (padded).
// 128x128 tile, BK=32, 4 waves, 32x32x16 MFMA, bf16x3 (Ah*Bh+Ah*Bl+Al*Bh).
// global_load_lds into 2-buffer LDS; counted vmcnt(8); raw barriers.
// MODE 0: split-write C into plane-tiled Ct              (K1)
// MODE 1: Cq[m,n] = bf16(r*acc - r*mu*u[n] + c[n])       (K3 fused-LN QKV)
// MODE 2: v = acc + bias[n] + Ct(hi+lo); split rewrite   (K4b residual accum)
// MODE 3: Cf[m,n] = acc + resid[m,n]                     (K5)
template <int MODE>
__global__ __launch_bounds__(256, 2) void gemm_ht(
    Op A, Op B, int nbx, int Kp, int N,
    float* __restrict__ Cf, int ldc,
    bf16* __restrict__ Cq,
    char* __restrict__ Ct, int CtR, int Ctrow0, int CtSub, int CtBig,
    const float* __restrict__ muP, const float* __restrict__ rsP,
    const float* __restrict__ uV, const float* __restrict__ cV,
    const float* __restrict__ bias,
    const float* __restrict__ resid, int ldr)
{
    __shared__ __align__(16) char lds[2][2][16384];   // [buf][A|B][128 rows x 128B]
    const int tid = threadIdx.x, w = tid >> 6, lane = tid & 63;

    // bijective XCD remap (m204), y-major bands: consecutive wg share n0.
    const int nwg = gridDim.x;
    const int qd = nwg >> 3, rm = nwg & 7;
    const int xc = blockIdx.x & 7, pos = blockIdx.x >> 3;
    const int wg = (xc < rm ? xc * (qd + 1) : rm * (qd + 1) + (xc - rm) * qd) + pos;
    const int m0 = (wg % nbx) * 128, n0 = (wg / nbx) * 128;

    // staging: instr i covers rows m0+w*32+i*8..+8; lane -> row r8, part p8.
    // source swizzle pp = p8 ^ r8 (involution with read-side XOR (lrow&7)<<4).
    // 128-row tiles never straddle a 2^subShift sub-block (128 | 2048).
    const int p8 = lane & 7, r8 = lane >> 3;
    const int pp = p8 ^ r8;
    const size_t psA = (size_t)A.R * 64, psB = (size_t)B.R * 64;
    const size_t lpA = (size_t)(pp >> 2) * psA + (size_t)(pp & 3) * 16;
    const size_t lpB = (size_t)(pp >> 2) * psB + (size_t)(pp & 3) * 16;
    const char* sA0 = A.base + lpA + rowOf(A, m0 + w * 32      + r8) * 64;
    const char* sA1 = A.base + lpA + rowOf(A, m0 + w * 32 + 8  + r8) * 64;
    const char* sA2 = A.base + lpA + rowOf(A, m0 + w * 32 + 16 + r8) * 64;
    const char* sA3 = A.base + lpA + rowOf(A, m0 + w * 32 + 24 + r8) * 64;
    const char* sB0 = B.base + lpB + rowOf(B, n0 + w * 32      + r8) * 64;
    const char* sB1 = B.base + lpB + rowOf(B, n0 + w * 32 + 8  + r8) * 64;
    const char* sB2 = B.base + lpB + rowOf(B, n0 + w * 32 + 16 + r8) * 64;
    const char* sB3 = B.base + lpB + rowOf(B, n0 + w * 32 + 24 + r8) * 64;

#define STAGE(buf, kt) do {                                                    \
        const size_t oA = (size_t)(2 * (kt)) * psA;                            \
        const size_t oB = (size_t)(2 * (kt)) * psB;                            \
        char* dA = &lds[buf][0][(w * 32) * 128];                               \
        char* dB = &lds[buf][1][(w * 32) * 128];                               \
        GLOAD16(sA0 + oA, dA);        GLOAD16(sA1 + oA, dA + 1024);            \
        GLOAD16(sA2 + oA, dA + 2048); GLOAD16(sA3 + oA, dA + 3072);            \
        GLOAD16(sB0 + oB, dB);        GLOAD16(sB1 + oB, dB + 1024);            \
        GLOAD16(sB2 + oB, dB + 2048); GLOAD16(sB3 + oB, dB + 3072);            \
    } while (0)

    // compute coords: wave (wr,wc) owns 64x64 = 2x2 of 32x32.
    const int wr = w >> 1, wc = w & 1;
    const int lrow = lane & 31, lkg = lane >> 5;
    const int swz = (lrow & 7) << 4;

    f32x16 acc[2][2];
#pragma unroll
    for (int i = 0; i < 2; ++i)
#pragma unroll
        for (int j = 0; j < 2; ++j)
#pragma unroll
            for (int r = 0; r < 16; ++r) acc[i][j][r] = 0.f;

    const int nk = Kp >> 5;
    STAGE(0, 0);
    int cur = 0;
#pragma unroll 1
    for (int kt = 0; kt < nk; ++kt) {
        const int ktn = (kt + 1 < nk) ? kt + 1 : kt;   // clamp: L2-hot reload
        STAGE(cur ^ 1, ktn);
        __builtin_amdgcn_sched_barrier(0);
        asm volatile("s_waitcnt vmcnt(8)" ::: "memory");   // cur's 8 landed
        __builtin_amdgcn_sched_barrier(0);
        __builtin_amdgcn_s_barrier();
        __builtin_amdgcn_sched_barrier(0);
        {
            bf16x8 ah[2][2], al[2][2], bh[2][2], bl[2][2];
#pragma unroll
            for (int f = 0; f < 2; ++f) {
                const char* baA = &lds[cur][0][(wr * 64 + f * 32 + lrow) * 128];
                const char* baB = &lds[cur][1][(wc * 64 + f * 32 + lrow) * 128];
#pragma unroll
                for (int g = 0; g < 2; ++g) {
                    const int off = g * 32 + lkg * 16;
                    ah[f][g] = *(const bf16x8*)(baA + ((off) ^ swz));
                    al[f][g] = *(const bf16x8*)(baA + ((64 + off) ^ swz));
                    bh[f][g] = *(const bf16x8*)(baB + ((off) ^ swz));
                    bl[f][g] = *(const bf16x8*)(baB + ((64 + off) ^ swz));
                }
            }
#pragma unroll
            for (int g = 0; g < 2; ++g)
#pragma unroll
                for (int fm = 0; fm < 2; ++fm)
#pragma unroll
                    for (int fn = 0; fn < 2; ++fn) {
                        acc[fm][fn] = __builtin_amdgcn_mfma_f32_32x32x16_bf16(
                            ah[fm][g], bh[fn][g], acc[fm][fn], 0, 0, 0);
                        acc[fm][fn] = __builtin_amdgcn_mfma_f32_32x32x16_bf16(
                            ah[fm][g], bl[fn][g], acc[fm][fn], 0, 0, 0);
                        acc[fm][fn] = __builtin_amdgcn_mfma_f32_32x32x16_bf16(
                            al[fm][g], bh[fn][g], acc[fm][fn], 0, 0, 0);
                    }
        }
        __builtin_amdgcn_sched_barrier(0);
        __builtin_amdgcn_s_barrier();                  // reads done before overwrite
        cur ^= 1;
    }
    asm volatile("s_waitcnt vmcnt(0)" ::: "memory");   // drain tail DMAs
#undef STAGE

    // epilogue. C/D map (verified r2/r4/r5): col=lane&31, row=(r&3)+8*(r>>2)+4*(lane>>5)
    const size_t psC = (size_t)CtR * 64;
    const int ctMask = (1 << CtSub) - 1;
#pragma unroll
    for (int fm = 0; fm < 2; ++fm)
#pragma unroll
        for (int fn = 0; fn < 2; ++fn) {
            const int gc = n0 + wc * 64 + fn * 32 + lrow;
            if (gc < N) {
#pragma unroll
                for (int r = 0; r < 16; ++r) {
                    const int gm = m0 + wr * 64 + fm * 32 + (r & 3) + 8 * (r >> 2) + 4 * lkg;
                    float v = acc[fm][fn][r];
                    if (MODE == 0 || MODE == 2) {
                        const size_t crow = (size_t)Ctrow0
                            + (size_t)(gm >> CtSub) * (size_t)CtBig + (gm & ctMask);
                        char* hp = Ct + (size_t)(2 * (gc >> 5)) * psC
                                 + crow * 64 + (gc & 31) * 2;
                        if (MODE == 2)
                            v += bias[gc] + (float)*(const bf16*)hp + (float)*(const bf16*)(hp + psC);
                        const bf16 h = (bf16)v;
                        *(bf16*)hp = h;
                        *(bf16*)(hp + psC) = (bf16)(v - (float)h);
                    } else if (MODE == 1) {
                        const size_t arow = rowOf(A, gm);   // LN stats are per-A-row
                        const float rr = rsP[arow], mm = muP[arow];
                        Cq[(size_t)gm * 1536 + gc] = (bf16)(rr * v - rr * mm * uV[gc] + cV[gc]);
                    } else {
                        Cf[(size_t)gm * ldc + gc] = v + resid[(size_t)gm * ldr + gc];
                    }
                }
            }
        }
}

// ---------------------------------------------------------------------------
// One wave per token: 4x4 DAG-masked MHA, 8 heads of 64. qkv bf16, chunk-local
// EXPERT-MAJOR rows [e*ntok + t][1536]; ctx written plane-tiled (R = 4*ntok,
// row = e*ntok + t).
__global__ __launch_bounds__(256) void attn_refine(
    const bf16* __restrict__ QKV, char* __restrict__ Ct, int ntok)
{
    const int w = threadIdx.x >> 6;
    const int lane = threadIdx.x & 63;
    const int t = blockIdx.x * 4 + w;
    if (t >= ntok) return;
    const bf16* __restrict__ b0 = QKV + (size_t)t * 1536;
    const size_t es = (size_t)ntok * 1536;
    const size_t ps = (size_t)(4 * ntok) * 64;
#pragma unroll
    for (int h = 0; h < 8; ++h) {
        const int off = h * 64 + lane;
        const float q1 = (float)b0[es + off];
        const float q2 = (float)b0[2 * es + off];
        const float q3 = (float)b0[3 * es + off];
        const float k0 = (float)b0[512 + off];
        const float k1 = (float)b0[es + 512 + off];
        const float k2 = (float)b0[2 * es + 512 + off];
        const float k3 = (float)b0[3 * es + 512 + off];
        const float v0 = (float)b0[1024 + off];
        const float v1 = (float)b0[es + 1024 + off];
        const float v2 = (float)b0[2 * es + 1024 + off];
        const float v3 = (float)b0[3 * es + 1024 + off];
        float s10 = q1 * k0, s11 = q1 * k1;
        float s20 = q2 * k0, s21 = q2 * k1, s22 = q2 * k2;
        float s30 = q3 * k0, s31 = q3 * k1, s32 = q3 * k2, s33 = q3 * k3;
#pragma unroll
        for (int o = 32; o > 0; o >>= 1) {
            s10 += __shfl_xor(s10, o); s11 += __shfl_xor(s11, o);
            s20 += __shfl_xor(s20, o); s21 += __shfl_xor(s21, o); s22 += __shfl_xor(s22, o);
            s30 += __shfl_xor(s30, o); s31 += __shfl_xor(s31, o);
            s32 += __shfl_xor(s32, o); s33 += __shfl_xor(s33, o);
        }
        const float sc = 0.125f;
        s10 *= sc; s11 *= sc;
        s20 *= sc; s21 *= sc; s22 *= sc;
        s30 *= sc; s31 *= sc; s32 *= sc; s33 *= sc;

        const float m1 = fmaxf(s10, s11);
        const float e10 = expf(s10 - m1), e11 = expf(s11 - m1);
        const float r1 = 1.f / (e10 + e11);
        const float m2 = fmaxf(fmaxf(s20, s21), s22);
        const float e20 = expf(s20 - m2), e21 = expf(s21 - m2), e22 = expf(s22 - m2);
        const float r2 = 1.f / (e20 + e21 + e22);
        const float m3 = fmaxf(fmaxf(s30, s31), fmaxf(s32, s33));
        const float e30 = expf(s30 - m3), e31 = expf(s31 - m3);
        const float e32 = expf(s32 - m3), e33 = expf(s33 - m3);
        const float r3 = 1.f / (e30 + e31 + e32 + e33);

        const float c0 = v0;
        const float c1 = (e10 * v0 + e11 * v1) * r1;
        const float c2 = (e20 * v0 + e21 * v1 + e22 * v2) * r2;
        const float c3 = (e30 * v0 + e31 * v1 + e32 * v2 + e33 * v3) * r3;
#pragma unroll
        for (int e = 0; e < 4; ++e) {
            const float cv = (e == 0) ? c0 : (e == 1) ? c1 : (e == 2) ? c2 : c3;
            char* hp = Ct + (size_t)(2 * (off >> 5)) * ps
                     + (size_t)(e * ntok + t) * 64 + (off & 31) * 2;
            const bf16 hh = (bf16)cv;
            *(bf16*)hp = hh;
            *(bf16*)(hp + ps) = (bf16)(cv - (float)hh);
        }
    }
}

// ---------------------------------------------------------------------------
extern "C" void kernel_launch(void* const* d_in, const int* in_sizes, int n_in,
                              void* d_out, int out_size, void* d_ws, size_t ws_size,
                              hipStream_t stream)
{
    (void)in_sizes; (void)n_in; (void)out_size; (void)ws_size;
    const float* x[4]    = {(const float*)d_in[0], (const float*)d_in[3],
                            (const float*)d_in[6], (const float*)d_in[9]};
    const float* Win[4]  = {(const float*)d_in[1], (const float*)d_in[4],
                            (const float*)d_in[7], (const float*)d_in[10]};
    const float* Wout[4] = {(const float*)d_in[2], (const float*)d_in[5],
                            (const float*)d_in[8], (const float*)d_in[11]};
    const float* ln_g = (const float*)d_in[12];
    const float* ln_b = (const float*)d_in[13];
    const float* Wqkv = (const float*)d_in[14];
    const float* bqkv = (const float*)d_in[15];
    const float* Wo   = (const float*)d_in[16];
    const float* bo   = (const float*)d_in[17];
    float* out = (float*)d_out;

    const int dE[4]  = {128, 128, 1006, 104};
    const int KpE[4] = {128, 128, 1024, 128};
    const int NTOK = 16384, ROWS = 65536;
    const int TPC = 2048, RPC = TPC * 4, XR = 8192;   // fixed (~187 MiB < proven ws)

    auto tbytes = [](int Rp, int Kp) { return (size_t)(Kp >> 4) * Rp * 64; };

    char* p = (char*)d_ws;
    auto alloc = [&](size_t bytes) -> char* {
        char* q = p; p += (bytes + 255) & ~(size_t)255; return q;
    };
    char* S = alloc(tbytes(ROWS, 512));               // 134 MB, row = e*NTOK + t
    char *WiT[4], *WoTt[4];
    for (int e = 0; e < 4; ++e) WiT[e]  = alloc(tbytes(512, KpE[e]));
    char* WgT = alloc(tbytes(1536, 512));
    char* WoT = alloc(tbytes(512, 512));
    for (int e = 0; e < 4; ++e) WoTt[e] = alloc(tbytes(KpE[e], 512));
    float* mu   = (float*)alloc((size_t)ROWS * 4);
    float* rstd = (float*)alloc((size_t)ROWS * 4);
    float* uV   = (float*)alloc(1536 * 4);
    float* cV   = (float*)alloc(1536 * 4);
    char* U = p;                                      // scratch: max ~42 MiB

    auto splitLaunch = [&](const float* in, int R, int K, int ldin,
                           char* ob, int Rp, int Kp, const float* cs) {
        const int total8 = (Rp * Kp) >> 3;
        int blocks = (total8 + 255) / 256; if (blocks > 4096) blocks = 4096;
        split_tiled<<<blocks, 256, 0, stream>>>(in, R, K, ldin, ob, Rp, Kp, cs);
    };

    // ---- weight prep ----
    for (int e = 0; e < 4; ++e)
        splitLaunch(Win[e], 512, dE[e], dE[e], WiT[e], 512, KpE[e], nullptr);
    splitLaunch(Wqkv, 1536, 512, 512, WgT, 1536, 512, ln_g);
    splitLaunch(Wo, 512, 512, 512, WoT, 512, 512, nullptr);
    for (int e = 0; e < 4; ++e)
        splitLaunch(Wout[e], dE[e], 512, 512, WoTt[e], KpE[e], 512, nullptr);
    qkv_uc<<<1536 / 4, 256, 0, stream>>>(Wqkv, ln_g, ln_b, bqkv, uV, cV);

    // ---- K1: x_e @ Win_e^T -> S rows e*NTOK + t (contiguous writes) ----
    for (int e = 0; e < 4; ++e) {
        const int rowsPer = (e == 2) ? XR : NTOK;
        for (int t0 = 0; t0 < NTOK; t0 += rowsPer) {
            splitLaunch(x[e] + (size_t)t0 * dE[e], rowsPer, dE[e], dE[e],
                        U, rowsPer, KpE[e], nullptr);
            const int nbx = rowsPer / 128;
            Op Ax{U, rowsPer, 0, 30, 0};
            Op Bx{WiT[e], 512, 0, 30, 0};
            gemm_ht<0><<<nbx * 4, 256, 0, stream>>>(
                Ax, Bx, nbx, KpE[e], 512,
                nullptr, 0, nullptr, S, ROWS, e * NTOK + t0, 30, 0,
                nullptr, nullptr, nullptr, nullptr, nullptr, nullptr, 0);
        }
    }

    // ---- K2: LN stats (rows expert-major, same as S) ----
    ln_stats_t<<<ROWS / 4, 256, 0, stream>>>(S, ROWS, mu, rstd);

    // ---- chunks: QKV (fused LN) -> attn -> Wo (+residual into S) ----
    // chunk-local logical row m = e*TPC + tt  ->  S row c*TPC + (m>>11)*NTOK + (m&2047)
    bf16* QKVc = (bf16*)U;                              // 25 MB
    char* CTXt = U + (size_t)RPC * 1536 * 2;            // 17 MB tiled
    for (int c = 0; c < NTOK / TPC; ++c) {
        const int rb = c * TPC;
        Op Aq{S, ROWS, rb, 11, NTOK};
        Op Bq{WgT, 1536, 0, 30, 0};
        gemm_ht<1><<<(RPC / 128) * 12, 256, 0, stream>>>(
            Aq, Bq, RPC / 128, 512, 1536,
            nullptr, 0, QKVc, nullptr, 0, 0, 30, 0,
            mu, rstd, uV, cV, nullptr, nullptr, 0);
        attn_refine<<<TPC / 4, 256, 0, stream>>>(QKVc, CTXt, TPC);
        Op Ac{CTXt, RPC, 0, 30, 0};
        Op Bo{WoT, 512, 0, 30, 0};
        gemm_ht<2><<<(RPC / 128) * 4, 256, 0, stream>>>(
            Ac, Bo, RPC / 128, 512, 512,
            nullptr, 0, nullptr, S, ROWS, rb, 11, NTOK,
            nullptr, nullptr, nullptr, nullptr, bo, nullptr, 0);
    }

    // ---- K5: out_e = S_e @ Wout_e^T + x_e (A contiguous now) ----
    size_t off = 0;
    for (int e = 0; e < 4; ++e) {
        Op As{S, ROWS, e * NTOK, 30, 0};
        Op Bw{WoTt[e], KpE[e], 0, 30, 0};
        gemm_ht<3><<<(NTOK / 128) * (KpE[e] / 128), 256, 0, stream>>>(
            As, Bw, NTOK / 128, 512, dE[e],
            out + off, dE[e], nullptr, nullptr, 0, 0, 30, 0,
            nullptr, nullptr, nullptr, nullptr, nullptr, x[e], dE[e]);
        off += (size_t)NTOK * dE[e];
    }
}

// Round 7
// 1086.758 us; speedup vs baseline: 1.2726x; 1.2726x over previous
//
#include <hip/hip_runtime.h>
#include <hip/hip_bf16.h>
#include <stdint.h>

// CrossExpertRefinement on MI355X — round 7: mixed-precision GEMM segments.
// K1 (input proj) = bf16x3 (SEGS=3, BK=32) — protects S / LN-stat precision.
// K3/K4b/K5 = single-bf16 hi-plane (SEGS=1, BK=64) — error ~2e-3, same scale
// as the already-accepted bf16 QKV storage rounding. Same staging macro, LDS
// shape, swizzle, vmcnt(8) pipeline, XCD banding and epilogues as round 6.
//
// Plane-tiled operand layout: element (row,k) hi byte =
//   base + (2*(k>>5))*R*64 + row*64 + (k&31)*2 ; lo plane at +R*64.

using bf16   = __bf16;
using bf16x8 = __attribute__((ext_vector_type(8))) __bf16;
using f32x16 = __attribute__((ext_vector_type(16))) float;

#define GLOAD16(g, l) __builtin_amdgcn_global_load_lds(                        \
    (const __attribute__((address_space(1))) unsigned int*)(g),                \
    (__attribute__((address_space(3))) unsigned int*)(l), 16, 0, 0)

// two-level logical-row -> physical-row map: sub-blocks of 2^subShift rows
// are contiguous (stride 1), blocks are bigStride apart.
struct Op { const char* base; int R; int row0; int subShift; int bigStride; };

__device__ __forceinline__ size_t rowOf(const Op& o, int m) {
    return (size_t)o.row0 + (size_t)(m >> o.subShift) * (size_t)o.bigStride
         + (size_t)(m & ((1u << o.subShift) - 1));
}

// ---------------------------------------------------------------------------
// fp32 (R x K, ld=ldin) -> plane-tiled hi/lo bf16, zero-padded to Rp x Kp.
__global__ __launch_bounds__(256) void split_tiled(
    const float* __restrict__ in, int R, int K, int ldin,
    char* __restrict__ outb, int Rp, int Kp, const float* __restrict__ cs)
{
    const size_t ps = (size_t)Rp * 64;
    const int total8 = (Rp * Kp) >> 3;
    for (int idx = blockIdx.x * 256 + threadIdx.x; idx < total8;
         idx += gridDim.x * 256) {
        const int r  = (idx << 3) / Kp;
        const int k8 = (idx << 3) - r * Kp;
        float v[8];
#pragma unroll
        for (int j = 0; j < 8; ++j) {
            const int k = k8 + j;
            float x = (r < R && k < K) ? in[(size_t)r * ldin + k] : 0.f;
            if (cs && k < K) x *= cs[k];
            v[j] = x;
        }
        bf16x8 h8, l8;
#pragma unroll
        for (int j = 0; j < 8; ++j) {
            const bf16 h = (bf16)v[j];
            h8[j] = h;
            l8[j] = (bf16)(v[j] - (float)h);
        }
        char* hp = outb + (size_t)(2 * (k8 >> 5)) * ps + (size_t)r * 64 + (k8 & 31) * 2;
        *(bf16x8*)hp = h8;
        *(bf16x8*)(hp + ps) = l8;
    }
}

// u[n] = Wqkv[n,:]·ln_g ; c[n] = Wqkv[n,:]·ln_b + bqkv[n]
__global__ __launch_bounds__(256) void qkv_uc(
    const float* __restrict__ W, const float* __restrict__ g,
    const float* __restrict__ b, const float* __restrict__ bq,
    float* __restrict__ u, float* __restrict__ c)
{
    const int n = blockIdx.x * 4 + (threadIdx.x >> 6);
    const int lane = threadIdx.x & 63;
    float su = 0.f, sc = 0.f;
#pragma unroll
    for (int j = 0; j < 8; ++j) {
        const int k = lane * 8 + j;
        const float w = W[(size_t)n * 512 + k];
        su += w * g[k];
        sc += w * b[k];
    }
#pragma unroll
    for (int o = 32; o > 0; o >>= 1) { su += __shfl_xor(su, o); sc += __shfl_xor(sc, o); }
    if (lane == 0) { u[n] = su; c[n] = sc + bq[n]; }
}

// Per-row LN stats from plane-tiled S (Kp=512). One wave per row.
__global__ __launch_bounds__(256) void ln_stats_t(
    const char* __restrict__ St, int R, float* __restrict__ mu, float* __restrict__ rstd)
{
    const int row = blockIdx.x * 4 + (threadIdx.x >> 6);
    const int lane = threadIdx.x & 63;
    const int kt = lane >> 2, qq = lane & 3;
    const size_t ps = (size_t)R * 64;
    const char* hp = St + (size_t)(2 * kt) * ps + (size_t)row * 64 + qq * 16;
    const bf16x8 h = *(const bf16x8*)hp;
    const bf16x8 l = *(const bf16x8*)(hp + ps);
    float s = 0.f, q = 0.f;
#pragma unroll
    for (int j = 0; j < 8; ++j) {
        const float v = (float)h[j] + (float)l[j];
        s += v; q += v * v;
    }
#pragma unroll
    for (int o = 32; o > 0; o >>= 1) { s += __shfl_xor(s, o); q += __shfl_xor(q, o); }
    if (lane == 0) {
        const float m = s * (1.f / 512.f);
        mu[row] = m;
        rstd[row] = rsqrtf(q * (1.f / 512.f) - m * m + 1e-5f);
    }
}

// ---------------------------------------------------------------------------
// GEMM C[m,n] = sum_k A[m,k]*B[n,k]; A,B plane-tiled hi/lo bf16 (padded).
// 128x128 tile, 4 waves, 32x32x16 MFMA.
// SEGS=3: BK=32, LDS row 128B = [hi 64B | lo 64B], 24 MFMA/step (bf16x3).
// SEGS=1: BK=64, LDS row 128B = hi k0..63,       16 MFMA/step (single bf16).
// global_load_lds into 2-buffer LDS; counted vmcnt(8); raw barriers.
// MODE 0: split-write C into plane-tiled Ct              (K1)
// MODE 1: Cq[m,n] = bf16(r*acc - r*mu*u[n] + c[n])       (K3 fused-LN QKV)
// MODE 2: v = acc + bias[n] + Ct(hi+lo); split rewrite   (K4b residual accum)
// MODE 3: Cf[m,n] = acc + resid[m,n]                     (K5)
template <int MODE, int SEGS>
__global__ __launch_bounds__(256, 2) void gemm_ht(
    Op A, Op B, int nbx, int Kp, int N,
    float* __restrict__ Cf, int ldc,
    bf16* __restrict__ Cq,
    char* __restrict__ Ct, int CtR, int Ctrow0, int CtSub, int CtBig,
    const float* __restrict__ muP, const float* __restrict__ rsP,
    const float* __restrict__ uV, const float* __restrict__ cV,
    const float* __restrict__ bias,
    const float* __restrict__ resid, int ldr)
{
    constexpr int NG = (SEGS == 3) ? 2 : 4;   // 16-k groups read per row
    constexpr int PM = (SEGS == 3) ? 2 : 4;   // planes advanced per k-step
    constexpr int LF = (SEGS == 3) ? 1 : 2;   // plane factor for unit offset
    __shared__ __align__(16) char lds[2][2][16384];   // [buf][A|B][128 x 128B]
    const int tid = threadIdx.x, w = tid >> 6, lane = tid & 63;

    // bijective XCD remap (m204), y-major bands.
    const int nwg = gridDim.x;
    const int qd = nwg >> 3, rm = nwg & 7;
    const int xc = blockIdx.x & 7, pos = blockIdx.x >> 3;
    const int wg = (xc < rm ? xc * (qd + 1) : rm * (qd + 1) + (xc - rm) * qd) + pos;
    const int m0 = (wg % nbx) * 128, n0 = (wg / nbx) * 128;

    // staging: instr i covers rows m0+w*32+i*8..+8; lane -> row r8, unit p8.
    // source swizzle pp = p8 ^ r8 (involution with read-side XOR (lrow&7)<<4).
    const int p8 = lane & 7, r8 = lane >> 3;
    const int pp = p8 ^ r8;
    const size_t psA = (size_t)A.R * 64, psB = (size_t)B.R * 64;
    const size_t lpA = (size_t)(pp >> 2) * psA * LF + (size_t)(pp & 3) * 16;
    const size_t lpB = (size_t)(pp >> 2) * psB * LF + (size_t)(pp & 3) * 16;
    const char* sA0 = A.base + lpA + rowOf(A, m0 + w * 32      + r8) * 64;
    const char* sA1 = A.base + lpA + rowOf(A, m0 + w * 32 + 8  + r8) * 64;
    const char* sA2 = A.base + lpA + rowOf(A, m0 + w * 32 + 16 + r8) * 64;
    const char* sA3 = A.base + lpA + rowOf(A, m0 + w * 32 + 24 + r8) * 64;
    const char* sB0 = B.base + lpB + rowOf(B, n0 + w * 32      + r8) * 64;
    const char* sB1 = B.base + lpB + rowOf(B, n0 + w * 32 + 8  + r8) * 64;
    const char* sB2 = B.base + lpB + rowOf(B, n0 + w * 32 + 16 + r8) * 64;
    const char* sB3 = B.base + lpB + rowOf(B, n0 + w * 32 + 24 + r8) * 64;

#define STAGE(buf, kt) do {                                                    \
        const size_t oA = (size_t)(PM * (kt)) * psA;                           \
        const size_t oB = (size_t)(PM * (kt)) * psB;                           \
        char* dA = &lds[buf][0][(w * 32) * 128];                               \
        char* dB = &lds[buf][1][(w * 32) * 128];                               \
        GLOAD16(sA0 + oA, dA);        GLOAD16(sA1 + oA, dA + 1024);            \
        GLOAD16(sA2 + oA, dA + 2048); GLOAD16(sA3 + oA, dA + 3072);            \
        GLOAD16(sB0 + oB, dB);        GLOAD16(sB1 + oB, dB + 1024);            \
        GLOAD16(sB2 + oB, dB + 2048); GLOAD16(sB3 + oB, dB + 3072);            \
    } while (0)

    // compute coords: wave (wr,wc) owns 64x64 = 2x2 of 32x32.
    const int wr = w >> 1, wc = w & 1;
    const int lrow = lane & 31, lkg = lane >> 5;
    const int swz = (lrow & 7) << 4;

    f32x16 acc[2][2];
#pragma unroll
    for (int i = 0; i < 2; ++i)
#pragma unroll
        for (int j = 0; j < 2; ++j)
#pragma unroll
            for (int r = 0; r < 16; ++r) acc[i][j][r] = 0.f;

    const int nk = Kp / ((SEGS == 3) ? 32 : 64);
    STAGE(0, 0);
    int cur = 0;
#pragma unroll 1
    for (int kt = 0; kt < nk; ++kt) {
        const int ktn = (kt + 1 < nk) ? kt + 1 : kt;   // clamp: L2-hot reload
        STAGE(cur ^ 1, ktn);
        __builtin_amdgcn_sched_barrier(0);
        asm volatile("s_waitcnt vmcnt(8)" ::: "memory");   // cur's 8 landed
        __builtin_amdgcn_sched_barrier(0);
        __builtin_amdgcn_s_barrier();
        __builtin_amdgcn_sched_barrier(0);
        {
            bf16x8 ah[2][NG], bh[2][NG], al[2][NG], bl[2][NG];
#pragma unroll
            for (int f = 0; f < 2; ++f) {
                const char* baA = &lds[cur][0][(wr * 64 + f * 32 + lrow) * 128];
                const char* baB = &lds[cur][1][(wc * 64 + f * 32 + lrow) * 128];
#pragma unroll
                for (int g = 0; g < NG; ++g) {
                    const int off = g * 32 + lkg * 16;
                    ah[f][g] = *(const bf16x8*)(baA + ((off) ^ swz));
                    bh[f][g] = *(const bf16x8*)(baB + ((off) ^ swz));
                    if (SEGS == 3) {
                        al[f][g] = *(const bf16x8*)(baA + ((64 + off) ^ swz));
                        bl[f][g] = *(const bf16x8*)(baB + ((64 + off) ^ swz));
                    }
                }
            }
#pragma unroll
            for (int g = 0; g < NG; ++g)
#pragma unroll
                for (int fm = 0; fm < 2; ++fm)
#pragma unroll
                    for (int fn = 0; fn < 2; ++fn) {
                        acc[fm][fn] = __builtin_amdgcn_mfma_f32_32x32x16_bf16(
                            ah[fm][g], bh[fn][g], acc[fm][fn], 0, 0, 0);
                        if (SEGS == 3) {
                            acc[fm][fn] = __builtin_amdgcn_mfma_f32_32x32x16_bf16(
                                ah[fm][g], bl[fn][g], acc[fm][fn], 0, 0, 0);
                            acc[fm][fn] = __builtin_amdgcn_mfma_f32_32x32x16_bf16(
                                al[fm][g], bh[fn][g], acc[fm][fn], 0, 0, 0);
                        }
                    }
        }
        __builtin_amdgcn_sched_barrier(0);
        __builtin_amdgcn_s_barrier();                  // reads done before overwrite
        cur ^= 1;
    }
    asm volatile("s_waitcnt vmcnt(0)" ::: "memory");   // drain tail DMAs
#undef STAGE

    // epilogue. C/D map (verified r2/r4/r5/r6): col=lane&31,
    // row=(r&3)+8*(r>>2)+4*(lane>>5)
    const size_t psC = (size_t)CtR * 64;
    const int ctMask = (1 << CtSub) - 1;
#pragma unroll
    for (int fm = 0; fm < 2; ++fm)
#pragma unroll
        for (int fn = 0; fn < 2; ++fn) {
            const int gc = n0 + wc * 64 + fn * 32 + lrow;
            if (gc < N) {
#pragma unroll
                for (int r = 0; r < 16; ++r) {
                    const int gm = m0 + wr * 64 + fm * 32 + (r & 3) + 8 * (r >> 2) + 4 * lkg;
                    float v = acc[fm][fn][r];
                    if (MODE == 0 || MODE == 2) {
                        const size_t crow = (size_t)Ctrow0
                            + (size_t)(gm >> CtSub) * (size_t)CtBig + (gm & ctMask);
                        char* hp = Ct + (size_t)(2 * (gc >> 5)) * psC
                                 + crow * 64 + (gc & 31) * 2;
                        if (MODE == 2)
                            v += bias[gc] + (float)*(const bf16*)hp + (float)*(const bf16*)(hp + psC);
                        const bf16 h = (bf16)v;
                        *(bf16*)hp = h;
                        *(bf16*)(hp + psC) = (bf16)(v - (float)h);
                    } else if (MODE == 1) {
                        const size_t arow = rowOf(A, gm);   // LN stats per A-row
                        const float rr = rsP[arow], mm = muP[arow];
                        Cq[(size_t)gm * 1536 + gc] = (bf16)(rr * v - rr * mm * uV[gc] + cV[gc]);
                    } else {
                        Cf[(size_t)gm * ldc + gc] = v + resid[(size_t)gm * ldr + gc];
                    }
                }
            }
        }
}

// ---------------------------------------------------------------------------
// One wave per token: 4x4 DAG-masked MHA, 8 heads of 64. qkv bf16, chunk-local
// EXPERT-MAJOR rows [e*ntok + t][1536]; ctx hi plane only (K4b is SEGS=1).
__global__ __launch_bounds__(256) void attn_refine(
    const bf16* __restrict__ QKV, char* __restrict__ Ct, int ntok)
{
    const int w = threadIdx.x >> 6;
    const int lane = threadIdx.x & 63;
    const int t = blockIdx.x * 4 + w;
    if (t >= ntok) return;
    const bf16* __restrict__ b0 = QKV + (size_t)t * 1536;
    const size_t es = (size_t)ntok * 1536;
    const size_t ps = (size_t)(4 * ntok) * 64;
#pragma unroll
    for (int h = 0; h < 8; ++h) {
        const int off = h * 64 + lane;
        const float q1 = (float)b0[es + off];
        const float q2 = (float)b0[2 * es + off];
        const float q3 = (float)b0[3 * es + off];
        const float k0 = (float)b0[512 + off];
        const float k1 = (float)b0[es + 512 + off];
        const float k2 = (float)b0[2 * es + 512 + off];
        const float k3 = (float)b0[3 * es + 512 + off];
        const float v0 = (float)b0[1024 + off];
        const float v1 = (float)b0[es + 1024 + off];
        const float v2 = (float)b0[2 * es + 1024 + off];
        const float v3 = (float)b0[3 * es + 1024 + off];
        float s10 = q1 * k0, s11 = q1 * k1;
        float s20 = q2 * k0, s21 = q2 * k1, s22 = q2 * k2;
        float s30 = q3 * k0, s31 = q3 * k1, s32 = q3 * k2, s33 = q3 * k3;
#pragma unroll
        for (int o = 32; o > 0; o >>= 1) {
            s10 += __shfl_xor(s10, o); s11 += __shfl_xor(s11, o);
            s20 += __shfl_xor(s20, o); s21 += __shfl_xor(s21, o); s22 += __shfl_xor(s22, o);
            s30 += __shfl_xor(s30, o); s31 += __shfl_xor(s31, o);
            s32 += __shfl_xor(s32, o); s33 += __shfl_xor(s33, o);
        }
        const float sc = 0.125f;
        s10 *= sc; s11 *= sc;
        s20 *= sc; s21 *= sc; s22 *= sc;
        s30 *= sc; s31 *= sc; s32 *= sc; s33 *= sc;

        const float m1 = fmaxf(s10, s11);
        const float e10 = expf(s10 - m1), e11 = expf(s11 - m1);
        const float r1 = 1.f / (e10 + e11);
        const float m2 = fmaxf(fmaxf(s20, s21), s22);
        const float e20 = expf(s20 - m2), e21 = expf(s21 - m2), e22 = expf(s22 - m2);
        const float r2 = 1.f / (e20 + e21 + e22);
        const float m3 = fmaxf(fmaxf(s30, s31), fmaxf(s32, s33));
        const float e30 = expf(s30 - m3), e31 = expf(s31 - m3);
        const float e32 = expf(s32 - m3), e33 = expf(s33 - m3);
        const float r3 = 1.f / (e30 + e31 + e32 + e33);

        const float c0 = v0;
        const float c1 = (e10 * v0 + e11 * v1) * r1;
        const float c2 = (e20 * v0 + e21 * v1 + e22 * v2) * r2;
        const float c3 = (e30 * v0 + e31 * v1 + e32 * v2 + e33 * v3) * r3;
#pragma unroll
        for (int e = 0; e < 4; ++e) {
            const float cv = (e == 0) ? c0 : (e == 1) ? c1 : (e == 2) ? c2 : c3;
            char* hp = Ct + (size_t)(2 * (off >> 5)) * ps
                     + (size_t)(e * ntok + t) * 64 + (off & 31) * 2;
            *(bf16*)hp = (bf16)cv;              // hi plane only (K4b reads hi)
        }
    }
}

// ---------------------------------------------------------------------------
extern "C" void kernel_launch(void* const* d_in, const int* in_sizes, int n_in,
                              void* d_out, int out_size, void* d_ws, size_t ws_size,
                              hipStream_t stream)
{
    (void)in_sizes; (void)n_in; (void)out_size; (void)ws_size;
    const float* x[4]    = {(const float*)d_in[0], (const float*)d_in[3],
                            (const float*)d_in[6], (const float*)d_in[9]};
    const float* Win[4]  = {(const float*)d_in[1], (const float*)d_in[4],
                            (const float*)d_in[7], (const float*)d_in[10]};
    const float* Wout[4] = {(const float*)d_in[2], (const float*)d_in[5],
                            (const float*)d_in[8], (const float*)d_in[11]};
    const float* ln_g = (const float*)d_in[12];
    const float* ln_b = (const float*)d_in[13];
    const float* Wqkv = (const float*)d_in[14];
    const float* bqkv = (const float*)d_in[15];
    const float* Wo   = (const float*)d_in[16];
    const float* bo   = (const float*)d_in[17];
    float* out = (float*)d_out;

    const int dE[4]  = {128, 128, 1006, 104};
    const int KpE[4] = {128, 128, 1024, 128};
    const int NTOK = 16384, ROWS = 65536;
    const int TPC = 2048, RPC = TPC * 4, XR = 8192;   // fixed (~187 MiB < proven ws)

    auto tbytes = [](int Rp, int Kp) { return (size_t)(Kp >> 4) * Rp * 64; };

    char* p = (char*)d_ws;
    auto alloc = [&](size_t bytes) -> char* {
        char* q = p; p += (bytes + 255) & ~(size_t)255; return q;
    };
    char* S = alloc(tbytes(ROWS, 512));               // 134 MB, row = e*NTOK + t
    char *WiT[4], *WoTt[4];
    for (int e = 0; e < 4; ++e) WiT[e]  = alloc(tbytes(512, KpE[e]));
    char* WgT = alloc(tbytes(1536, 512));
    char* WoT = alloc(tbytes(512, 512));
    for (int e = 0; e < 4; ++e) WoTt[e] = alloc(tbytes(KpE[e], 512));
    float* mu   = (float*)alloc((size_t)ROWS * 4);
    float* rstd = (float*)alloc((size_t)ROWS * 4);
    float* uV   = (float*)alloc(1536 * 4);
    float* cV   = (float*)alloc(1536 * 4);
    char* U = p;                                      // scratch: max ~42 MiB

    auto splitLaunch = [&](const float* in, int R, int K, int ldin,
                           char* ob, int Rp, int Kp, const float* cs) {
        const int total8 = (Rp * Kp) >> 3;
        int blocks = (total8 + 255) / 256; if (blocks > 4096) blocks = 4096;
        split_tiled<<<blocks, 256, 0, stream>>>(in, R, K, ldin, ob, Rp, Kp, cs);
    };

    // ---- weight prep ----
    for (int e = 0; e < 4; ++e)
        splitLaunch(Win[e], 512, dE[e], dE[e], WiT[e], 512, KpE[e], nullptr);
    splitLaunch(Wqkv, 1536, 512, 512, WgT, 1536, 512, ln_g);
    splitLaunch(Wo, 512, 512, 512, WoT, 512, 512, nullptr);
    for (int e = 0; e < 4; ++e)
        splitLaunch(Wout[e], dE[e], 512, 512, WoTt[e], KpE[e], 512, nullptr);
    qkv_uc<<<1536 / 4, 256, 0, stream>>>(Wqkv, ln_g, ln_b, bqkv, uV, cV);

    // ---- K1: x_e @ Win_e^T -> S rows e*NTOK + t (SEGS=3, precise) ----
    for (int e = 0; e < 4; ++e) {
        const int rowsPer = (e == 2) ? XR : NTOK;
        for (int t0 = 0; t0 < NTOK; t0 += rowsPer) {
            splitLaunch(x[e] + (size_t)t0 * dE[e], rowsPer, dE[e], dE[e],
                        U, rowsPer, KpE[e], nullptr);
            const int nbx = rowsPer / 128;
            Op Ax{U, rowsPer, 0, 30, 0};
            Op Bx{WiT[e], 512, 0, 30, 0};
            gemm_ht<0, 3><<<nbx * 4, 256, 0, stream>>>(
                Ax, Bx, nbx, KpE[e], 512,
                nullptr, 0, nullptr, S, ROWS, e * NTOK + t0, 30, 0,
                nullptr, nullptr, nullptr, nullptr, nullptr, nullptr, 0);
        }
    }

    // ---- K2: LN stats (rows expert-major, same as S) ----
    ln_stats_t<<<ROWS / 4, 256, 0, stream>>>(S, ROWS, mu, rstd);

    // ---- chunks: QKV (fused LN) -> attn -> Wo (+residual into S) ----
    // chunk-local logical row m = e*TPC + tt -> S row c*TPC + (m>>11)*NTOK + (m&2047)
    bf16* QKVc = (bf16*)U;                              // 25 MB
    char* CTXt = U + (size_t)RPC * 1536 * 2;            // 17 MB tiled
    for (int c = 0; c < NTOK / TPC; ++c) {
        const int rb = c * TPC;
        Op Aq{S, ROWS, rb, 11, NTOK};
        Op Bq{WgT, 1536, 0, 30, 0};
        gemm_ht<1, 1><<<(RPC / 128) * 12, 256, 0, stream>>>(
            Aq, Bq, RPC / 128, 512, 1536,
            nullptr, 0, QKVc, nullptr, 0, 0, 30, 0,
            mu, rstd, uV, cV, nullptr, nullptr, 0);
        attn_refine<<<TPC / 4, 256, 0, stream>>>(QKVc, CTXt, TPC);
        Op Ac{CTXt, RPC, 0, 30, 0};
        Op Bo{WoT, 512, 0, 30, 0};
        gemm_ht<2, 1><<<(RPC / 128) * 4, 256, 0, stream>>>(
            Ac, Bo, RPC / 128, 512, 512,
            nullptr, 0, nullptr, S, ROWS, rb, 11, NTOK,
            nullptr, nullptr, nullptr, nullptr, bo, nullptr, 0);
    }

    // ---- K5: out_e = S_e @ Wout_e^T + x_e (SEGS=1) ----
    size_t off = 0;
    for (int e = 0; e < 4; ++e) {
        Op As{S, ROWS, e * NTOK, 30, 0};
        Op Bw{WoTt[e], KpE[e], 0, 30, 0};
        gemm_ht<3, 1><<<(NTOK / 128) * (KpE[e] / 128), 256, 0, stream>>>(
            As, Bw, NTOK / 128, 512, dE[e],
            out + off, dE[e], nullptr, nullptr, 0, 0, 30, 0,
            nullptr, nullptr, nullptr, nullptr, nullptr, x[e], dE[e]);
        off += (size_t)NTOK * dE[e];
    }
}

// Round 8
// 791.854 us; speedup vs baseline: 1.7465x; 1.3724x over previous
//
#include <hip/hip_runtime.h>
#include <hip/hip_bf16.h>
#include <stdint.h>

// CrossExpertRefinement on MI355X — round 8: all-SEGS=1 single-bf16 GEMMs,
// hi-only plane-tiled operands, batched split kernel, TPC=4096 (4 chunks),
// 24 total dispatches. Core K-loop = r7's proven SEGS=1 path (BK=64, 128^2
// tile, 4 waves, 32x32x16 MFMA, global_load_lds dbuf, vmcnt(8), src-side
// swizzle, XCD banding). Fused LN / bias / residual epilogues.
//
// Hi-plane-tiled layout: element (row,k) = base + (k>>5)*R*64 + row*64 + (k&31)*2.

using bf16   = __bf16;
using bf16x8 = __attribute__((ext_vector_type(8))) __bf16;
using f32x16 = __attribute__((ext_vector_type(16))) float;

#define GLOAD16(g, l) __builtin_amdgcn_global_load_lds(                        \
    (const __attribute__((address_space(1))) unsigned int*)(g),                \
    (__attribute__((address_space(3))) unsigned int*)(l), 16, 0, 0)

// two-level logical-row -> physical-row map: sub-blocks of 2^subShift rows
// are contiguous (stride 1), blocks are bigStride apart.
struct Op { const char* base; int R; int row0; int subShift; int bigStride; };

__device__ __forceinline__ size_t rowOf(const Op& o, int m) {
    return (size_t)o.row0 + (size_t)(m >> o.subShift) * (size_t)o.bigStride
         + (size_t)(m & ((1u << o.subShift) - 1));
}

// ---------------------------------------------------------------------------
// Batched fp32 -> hi-bf16 plane-tiled split. Each job gets a block range.
struct SplitJob {
    const float* src; const float* cs; char* dst;
    int R, K, ldin, Rp, Kp, blk0;
};
struct SplitBatch { SplitJob j[10]; int njobs; };

__global__ __launch_bounds__(256) void split_batch(SplitBatch sb)
{
    int ji = 0;
#pragma unroll 1
    for (int i = 1; i < sb.njobs; ++i)
        if ((int)blockIdx.x >= sb.j[i].blk0) ji = i;
    const SplitJob J = sb.j[ji];
    const int nblk = ((ji + 1 < sb.njobs) ? sb.j[ji + 1].blk0 : (int)gridDim.x) - J.blk0;
    const size_t ps = (size_t)J.Rp * 64;
    const int total8 = (J.Rp * J.Kp) >> 3;
    for (int idx = ((int)blockIdx.x - J.blk0) * 256 + (int)threadIdx.x; idx < total8;
         idx += nblk * 256) {
        const int r  = (idx << 3) / J.Kp;
        const int k8 = (idx << 3) - r * J.Kp;
        bf16x8 h8;
#pragma unroll
        for (int j = 0; j < 8; ++j) {
            const int k = k8 + j;
            float x = (r < J.R && k < J.K) ? J.src[(size_t)r * J.ldin + k] : 0.f;
            if (J.cs && k < J.K) x *= J.cs[k];
            h8[j] = (bf16)x;
        }
        *(bf16x8*)(J.dst + (size_t)(k8 >> 5) * ps + (size_t)r * 64 + (k8 & 31) * 2) = h8;
    }
}

// u[n] = Wqkv[n,:]·ln_g ; c[n] = Wqkv[n,:]·ln_b + bqkv[n]
__global__ __launch_bounds__(256) void qkv_uc(
    const float* __restrict__ W, const float* __restrict__ g,
    const float* __restrict__ b, const float* __restrict__ bq,
    float* __restrict__ u, float* __restrict__ c)
{
    const int n = blockIdx.x * 4 + (threadIdx.x >> 6);
    const int lane = threadIdx.x & 63;
    float su = 0.f, sc = 0.f;
#pragma unroll
    for (int j = 0; j < 8; ++j) {
        const int k = lane * 8 + j;
        const float w = W[(size_t)n * 512 + k];
        su += w * g[k];
        sc += w * b[k];
    }
#pragma unroll
    for (int o = 32; o > 0; o >>= 1) { su += __shfl_xor(su, o); sc += __shfl_xor(sc, o); }
    if (lane == 0) { u[n] = su; c[n] = sc + bq[n]; }
}

// Per-row LN stats from hi-plane-tiled S (Kp=512 -> 16 planes). 1 wave/row.
__global__ __launch_bounds__(256) void ln_stats_t(
    const char* __restrict__ St, int R, float* __restrict__ mu, float* __restrict__ rstd)
{
    const int row = blockIdx.x * 4 + (threadIdx.x >> 6);
    const int lane = threadIdx.x & 63;
    const int kt = lane >> 2, qq = lane & 3;
    const size_t ps = (size_t)R * 64;
    const bf16x8 h = *(const bf16x8*)(St + (size_t)kt * ps + (size_t)row * 64 + qq * 16);
    float s = 0.f, q = 0.f;
#pragma unroll
    for (int j = 0; j < 8; ++j) {
        const float v = (float)h[j];
        s += v; q += v * v;
    }
#pragma unroll
    for (int o = 32; o > 0; o >>= 1) { s += __shfl_xor(s, o); q += __shfl_xor(q, o); }
    if (lane == 0) {
        const float m = s * (1.f / 512.f);
        mu[row] = m;
        rstd[row] = rsqrtf(q * (1.f / 512.f) - m * m + 1e-5f);
    }
}

// ---------------------------------------------------------------------------
// GEMM C[m,n] = sum_k A[m,k]*B[n,k]; A,B hi-plane-tiled bf16 (padded).
// 128x128 tile, BK=64, 4 waves, 16 MFMA/step. global_load_lds 2-buffer,
// counted vmcnt(8), raw barriers, src-side swizzle pp=p8^r8 vs read XOR.
// MODE 0: write C hi-plane-tiled into Ct                 (K1)
// MODE 1: Cq[m,n] = bf16(r*acc - r*mu*u[n] + c[n])       (K3 fused-LN QKV)
// MODE 2: v = acc + bias[n] + Ct_hi; rewrite hi          (K4b residual accum)
// MODE 3: Cf[m,n] = acc + resid[m,n]                     (K5)
template <int MODE>
__global__ __launch_bounds__(256, 2) void gemm_ht(
    Op A, Op B, int nbx, int Kp, int N,
    float* __restrict__ Cf, int ldc,
    bf16* __restrict__ Cq,
    char* __restrict__ Ct, int CtR, int Ctrow0, int CtSub, int CtBig,
    const float* __restrict__ muP, const float* __restrict__ rsP,
    const float* __restrict__ uV, const float* __restrict__ cV,
    const float* __restrict__ bias,
    const float* __restrict__ resid, int ldr)
{
    __shared__ __align__(16) char lds[2][2][16384];   // [buf][A|B][128 x 128B]
    const int tid = threadIdx.x, w = tid >> 6, lane = tid & 63;

    // bijective XCD remap (m204), y-major bands.
    const int nwg = gridDim.x;
    const int qd = nwg >> 3, rm = nwg & 7;
    const int xc = blockIdx.x & 7, pos = blockIdx.x >> 3;
    const int wg = (xc < rm ? xc * (qd + 1) : rm * (qd + 1) + (xc - rm) * qd) + pos;
    const int m0 = (wg % nbx) * 128, n0 = (wg / nbx) * 128;

    // staging: instr i covers rows m0+w*32+i*8..+8; lane -> row r8, unit p8.
    // LDS row 128B = [plane 2kt 64B | plane 2kt+1 64B]; source swizzle pp=p8^r8.
    const int p8 = lane & 7, r8 = lane >> 3;
    const int pp = p8 ^ r8;
    const size_t psA = (size_t)A.R * 64, psB = (size_t)B.R * 64;
    const size_t lpA = (size_t)(pp >> 2) * psA + (size_t)(pp & 3) * 16;
    const size_t lpB = (size_t)(pp >> 2) * psB + (size_t)(pp & 3) * 16;
    const char* sA0 = A.base + lpA + rowOf(A, m0 + w * 32      + r8) * 64;
    const char* sA1 = A.base + lpA + rowOf(A, m0 + w * 32 + 8  + r8) * 64;
    const char* sA2 = A.base + lpA + rowOf(A, m0 + w * 32 + 16 + r8) * 64;
    const char* sA3 = A.base + lpA + rowOf(A, m0 + w * 32 + 24 + r8) * 64;
    const char* sB0 = B.base + lpB + rowOf(B, n0 + w * 32      + r8) * 64;
    const char* sB1 = B.base + lpB + rowOf(B, n0 + w * 32 + 8  + r8) * 64;
    const char* sB2 = B.base + lpB + rowOf(B, n0 + w * 32 + 16 + r8) * 64;
    const char* sB3 = B.base + lpB + rowOf(B, n0 + w * 32 + 24 + r8) * 64;

#define STAGE(buf, kt) do {                                                    \
        const size_t oA = (size_t)(2 * (kt)) * psA;                            \
        const size_t oB = (size_t)(2 * (kt)) * psB;                            \
        char* dA = &lds[buf][0][(w * 32) * 128];                               \
        char* dB = &lds[buf][1][(w * 32) * 128];                               \
        GLOAD16(sA0 + oA, dA);        GLOAD16(sA1 + oA, dA + 1024);            \
        GLOAD16(sA2 + oA, dA + 2048); GLOAD16(sA3 + oA, dA + 3072);            \
        GLOAD16(sB0 + oB, dB);        GLOAD16(sB1 + oB, dB + 1024);            \
        GLOAD16(sB2 + oB, dB + 2048); GLOAD16(sB3 + oB, dB + 3072);            \
    } while (0)

    // compute coords: wave (wr,wc) owns 64x64 = 2x2 of 32x32.
    const int wr = w >> 1, wc = w & 1;
    const int lrow = lane & 31, lkg = lane >> 5;
    const int swz = (lrow & 7) << 4;

    f32x16 acc[2][2];
#pragma unroll
    for (int i = 0; i < 2; ++i)
#pragma unroll
        for (int j = 0; j < 2; ++j)
#pragma unroll
            for (int r = 0; r < 16; ++r) acc[i][j][r] = 0.f;

    const int nk = Kp >> 6;                 // BK = 64
    STAGE(0, 0);
    int cur = 0;
#pragma unroll 1
    for (int kt = 0; kt < nk; ++kt) {
        const int ktn = (kt + 1 < nk) ? kt + 1 : kt;   // clamp: L2-hot reload
        STAGE(cur ^ 1, ktn);
        __builtin_amdgcn_sched_barrier(0);
        asm volatile("s_waitcnt vmcnt(8)" ::: "memory");   // cur's 8 landed
        __builtin_amdgcn_sched_barrier(0);
        __builtin_amdgcn_s_barrier();
        __builtin_amdgcn_sched_barrier(0);
        {
            bf16x8 ah[2][4], bh[2][4];
#pragma unroll
            for (int f = 0; f < 2; ++f) {
                const char* baA = &lds[cur][0][(wr * 64 + f * 32 + lrow) * 128];
                const char* baB = &lds[cur][1][(wc * 64 + f * 32 + lrow) * 128];
#pragma unroll
                for (int g = 0; g < 4; ++g) {
                    const int off = g * 32 + lkg * 16;
                    ah[f][g] = *(const bf16x8*)(baA + (off ^ swz));
                    bh[f][g] = *(const bf16x8*)(baB + (off ^ swz));
                }
            }
#pragma unroll
            for (int g = 0; g < 4; ++g)
#pragma unroll
                for (int fm = 0; fm < 2; ++fm)
#pragma unroll
                    for (int fn = 0; fn < 2; ++fn)
                        acc[fm][fn] = __builtin_amdgcn_mfma_f32_32x32x16_bf16(
                            ah[fm][g], bh[fn][g], acc[fm][fn], 0, 0, 0);
        }
        __builtin_amdgcn_sched_barrier(0);
        __builtin_amdgcn_s_barrier();                  // reads done before overwrite
        cur ^= 1;
    }
    asm volatile("s_waitcnt vmcnt(0)" ::: "memory");   // drain tail DMAs
#undef STAGE

    // epilogue. C/D map (verified r2..r7): col=lane&31, row=(r&3)+8*(r>>2)+4*(lane>>5)
    const size_t psC = (size_t)CtR * 64;
    const int ctMask = (1 << CtSub) - 1;
#pragma unroll
    for (int fm = 0; fm < 2; ++fm)
#pragma unroll
        for (int fn = 0; fn < 2; ++fn) {
            const int gc = n0 + wc * 64 + fn * 32 + lrow;
            if (gc < N) {
#pragma unroll
                for (int r = 0; r < 16; ++r) {
                    const int gm = m0 + wr * 64 + fm * 32 + (r & 3) + 8 * (r >> 2) + 4 * lkg;
                    float v = acc[fm][fn][r];
                    if (MODE == 0 || MODE == 2) {
                        const size_t crow = (size_t)Ctrow0
                            + (size_t)(gm >> CtSub) * (size_t)CtBig + (gm & ctMask);
                        char* hp = Ct + (size_t)(gc >> 5) * psC
                                 + crow * 64 + (gc & 31) * 2;
                        if (MODE == 2)
                            v += bias[gc] + (float)*(const bf16*)hp;
                        *(bf16*)hp = (bf16)v;
                    } else if (MODE == 1) {
                        const size_t arow = rowOf(A, gm);   // LN stats per A-row
                        const float rr = rsP[arow], mm = muP[arow];
                        Cq[(size_t)gm * 1536 + gc] = (bf16)(rr * v - rr * mm * uV[gc] + cV[gc]);
                    } else {
                        Cf[(size_t)gm * ldc + gc] = v + resid[(size_t)gm * ldr + gc];
                    }
                }
            }
        }
}

// ---------------------------------------------------------------------------
// One wave per token: 4x4 DAG-masked MHA, 8 heads of 64. qkv bf16, chunk-local
// EXPERT-MAJOR rows [e*ntok + t][1536]; ctx hi-plane-tiled (R = 4*ntok).
__global__ __launch_bounds__(256) void attn_refine(
    const bf16* __restrict__ QKV, char* __restrict__ Ct, int ntok)
{
    const int w = threadIdx.x >> 6;
    const int lane = threadIdx.x & 63;
    const int t = blockIdx.x * 4 + w;
    if (t >= ntok) return;
    const bf16* __restrict__ b0 = QKV + (size_t)t * 1536;
    const size_t es = (size_t)ntok * 1536;
    const size_t ps = (size_t)(4 * ntok) * 64;
#pragma unroll
    for (int h = 0; h < 8; ++h) {
        const int off = h * 64 + lane;
        const float q1 = (float)b0[es + off];
        const float q2 = (float)b0[2 * es + off];
        const float q3 = (float)b0[3 * es + off];
        const float k0 = (float)b0[512 + off];
        const float k1 = (float)b0[es + 512 + off];
        const float k2 = (float)b0[2 * es + 512 + off];
        const float k3 = (float)b0[3 * es + 512 + off];
        const float v0 = (float)b0[1024 + off];
        const float v1 = (float)b0[es + 1024 + off];
        const float v2 = (float)b0[2 * es + 1024 + off];
        const float v3 = (float)b0[3 * es + 1024 + off];
        float s10 = q1 * k0, s11 = q1 * k1;
        float s20 = q2 * k0, s21 = q2 * k1, s22 = q2 * k2;
        float s30 = q3 * k0, s31 = q3 * k1, s32 = q3 * k2, s33 = q3 * k3;
#pragma unroll
        for (int o = 32; o > 0; o >>= 1) {
            s10 += __shfl_xor(s10, o); s11 += __shfl_xor(s11, o);
            s20 += __shfl_xor(s20, o); s21 += __shfl_xor(s21, o); s22 += __shfl_xor(s22, o);
            s30 += __shfl_xor(s30, o); s31 += __shfl_xor(s31, o);
            s32 += __shfl_xor(s32, o); s33 += __shfl_xor(s33, o);
        }
        const float sc = 0.125f;
        s10 *= sc; s11 *= sc;
        s20 *= sc; s21 *= sc; s22 *= sc;
        s30 *= sc; s31 *= sc; s32 *= sc; s33 *= sc;

        const float m1 = fmaxf(s10, s11);
        const float e10 = expf(s10 - m1), e11 = expf(s11 - m1);
        const float r1 = 1.f / (e10 + e11);
        const float m2 = fmaxf(fmaxf(s20, s21), s22);
        const float e20 = expf(s20 - m2), e21 = expf(s21 - m2), e22 = expf(s22 - m2);
        const float r2 = 1.f / (e20 + e21 + e22);
        const float m3 = fmaxf(fmaxf(s30, s31), fmaxf(s32, s33));
        const float e30 = expf(s30 - m3), e31 = expf(s31 - m3);
        const float e32 = expf(s32 - m3), e33 = expf(s33 - m3);
        const float r3 = 1.f / (e30 + e31 + e32 + e33);

        const float c0 = v0;
        const float c1 = (e10 * v0 + e11 * v1) * r1;
        const float c2 = (e20 * v0 + e21 * v1 + e22 * v2) * r2;
        const float c3 = (e30 * v0 + e31 * v1 + e32 * v2 + e33 * v3) * r3;
#pragma unroll
        for (int e = 0; e < 4; ++e) {
            const float cv = (e == 0) ? c0 : (e == 1) ? c1 : (e == 2) ? c2 : c3;
            *(bf16*)(Ct + (size_t)(off >> 5) * ps
                     + (size_t)(e * ntok + t) * 64 + (off & 31) * 2) = (bf16)cv;
        }
    }
}

// ---------------------------------------------------------------------------
extern "C" void kernel_launch(void* const* d_in, const int* in_sizes, int n_in,
                              void* d_out, int out_size, void* d_ws, size_t ws_size,
                              hipStream_t stream)
{
    (void)in_sizes; (void)n_in; (void)out_size; (void)ws_size;
    const float* x[4]    = {(const float*)d_in[0], (const float*)d_in[3],
                            (const float*)d_in[6], (const float*)d_in[9]};
    const float* Win[4]  = {(const float*)d_in[1], (const float*)d_in[4],
                            (const float*)d_in[7], (const float*)d_in[10]};
    const float* Wout[4] = {(const float*)d_in[2], (const float*)d_in[5],
                            (const float*)d_in[8], (const float*)d_in[11]};
    const float* ln_g = (const float*)d_in[12];
    const float* ln_b = (const float*)d_in[13];
    const float* Wqkv = (const float*)d_in[14];
    const float* bqkv = (const float*)d_in[15];
    const float* Wo   = (const float*)d_in[16];
    const float* bo   = (const float*)d_in[17];
    float* out = (float*)d_out;

    const int dE[4]  = {128, 128, 1006, 104};
    const int KpE[4] = {128, 128, 1024, 128};
    const int NTOK = 16384, ROWS = 65536;
    const int TPC = 4096, RPC = TPC * 4;              // 4 chunks

    auto tbytes = [](int Rp, int Kp) { return (size_t)Rp * Kp * 2; };  // hi only

    char* p = (char*)d_ws;
    auto alloc = [&](size_t bytes) -> char* {
        char* q = p; p += (bytes + 255) & ~(size_t)255; return q;
    };
    char* S = alloc(tbytes(ROWS, 512));               // 67 MB, row = e*NTOK + t
    char *WiT[4], *WoTt[4];
    for (int e = 0; e < 4; ++e) WiT[e]  = alloc(tbytes(512, KpE[e]));
    char* WgT = alloc(tbytes(1536, 512));
    char* WoT = alloc(tbytes(512, 512));
    for (int e = 0; e < 4; ++e) WoTt[e] = alloc(tbytes(KpE[e], 512));
    float* mu   = (float*)alloc((size_t)ROWS * 4);
    float* rstd = (float*)alloc((size_t)ROWS * 4);
    float* uV   = (float*)alloc(1536 * 4);
    float* cV   = (float*)alloc(1536 * 4);
    char* U = p;        // scratch: x-splits 46 MB, later QKV 50 + CTX 17 MB

    // ---- batched splits (2 launches total) ----
    SplitBatch sb{}; int grid = 0;
    auto addJob = [&](const float* src, const float* cs, char* dst,
                      int R, int K, int ldin, int Rp, int Kp) {
        const int total8 = (Rp * Kp) >> 3;
        int blocks = (total8 + 1023) / 1024;
        if (blocks < 1) blocks = 1;
        if (blocks > 1024) blocks = 1024;
        sb.j[sb.njobs++] = {src, cs, dst, R, K, ldin, Rp, Kp, grid};
        grid += blocks;
    };
    // weights (10 jobs, one launch)
    for (int e = 0; e < 4; ++e)
        addJob(Win[e], nullptr, WiT[e], 512, dE[e], dE[e], 512, KpE[e]);
    addJob(Wqkv, ln_g, WgT, 1536, 512, 512, 1536, 512);
    addJob(Wo, nullptr, WoT, 512, 512, 512, 512, 512);
    for (int e = 0; e < 4; ++e)
        addJob(Wout[e], nullptr, WoTt[e], dE[e], 512, 512, KpE[e], 512);
    split_batch<<<grid, 256, 0, stream>>>(sb);
    qkv_uc<<<1536 / 4, 256, 0, stream>>>(Wqkv, ln_g, ln_b, bqkv, uV, cV);

    // x inputs (4 jobs, one launch) into U
    char* xh[4]; { char* q = U; for (int e = 0; e < 4; ++e) { xh[e] = q; q += tbytes(NTOK, KpE[e]); } }
    sb = SplitBatch{}; grid = 0;
    for (int e = 0; e < 4; ++e)
        addJob(x[e], nullptr, xh[e], NTOK, dE[e], dE[e], NTOK, KpE[e]);
    split_batch<<<grid, 256, 0, stream>>>(sb);

    // ---- K1: x_e @ Win_e^T -> S rows e*NTOK + t ----
    for (int e = 0; e < 4; ++e) {
        Op Ax{xh[e], NTOK, 0, 30, 0};
        Op Bx{WiT[e], 512, 0, 30, 0};
        gemm_ht<0><<<(NTOK / 128) * 4, 256, 0, stream>>>(
            Ax, Bx, NTOK / 128, KpE[e], 512,
            nullptr, 0, nullptr, S, ROWS, e * NTOK, 30, 0,
            nullptr, nullptr, nullptr, nullptr, nullptr, nullptr, 0);
    }

    // ---- K2: LN stats ----
    ln_stats_t<<<ROWS / 4, 256, 0, stream>>>(S, ROWS, mu, rstd);

    // ---- chunks: QKV (fused LN) -> attn -> Wo (+residual into S) ----
    // chunk-local logical row m = e*TPC + tt -> S row c*TPC + (m>>12)*NTOK + (m&4095)
    bf16* QKVc = (bf16*)U;                              // 50 MB
    char* CTXt = U + (size_t)RPC * 1536 * 2;            // 17 MB hi-tiled
    for (int c = 0; c < NTOK / TPC; ++c) {
        const int rb = c * TPC;
        Op Aq{S, ROWS, rb, 12, NTOK};
        Op Bq{WgT, 1536, 0, 30, 0};
        gemm_ht<1><<<(RPC / 128) * 12, 256, 0, stream>>>(
            Aq, Bq, RPC / 128, 512, 1536,
            nullptr, 0, QKVc, nullptr, 0, 0, 30, 0,
            mu, rstd, uV, cV, nullptr, nullptr, 0);
        attn_refine<<<TPC / 4, 256, 0, stream>>>(QKVc, CTXt, TPC);
        Op Ac{CTXt, RPC, 0, 30, 0};
        Op Bo{WoT, 512, 0, 30, 0};
        gemm_ht<2><<<(RPC / 128) * 4, 256, 0, stream>>>(
            Ac, Bo, RPC / 128, 512, 512,
            nullptr, 0, nullptr, S, ROWS, rb, 12, NTOK,
            nullptr, nullptr, nullptr, nullptr, bo, nullptr, 0);
    }

    // ---- K5: out_e = S_e @ Wout_e^T + x_e ----
    size_t off = 0;
    for (int e = 0; e < 4; ++e) {
        Op As{S, ROWS, e * NTOK, 30, 0};
        Op Bw{WoTt[e], KpE[e], 0, 30, 0};
        gemm_ht<3><<<(NTOK / 128) * (KpE[e] / 128), 256, 0, stream>>>(
            As, Bw, NTOK / 128, 512, dE[e],
            out + off, dE[e], nullptr, nullptr, 0, 0, 30, 0,
            nullptr, nullptr, nullptr, nullptr, nullptr, x[e], dE[e]);
        off += (size_t)NTOK * dE[e];
    }
}